// Round 2
// baseline (77.989 us; speedup 1.0000x reference)
//
#include <hip/hip_runtime.h>

#define MB   2048   // model batches
#define NP   8192   // num points (scan length)
#define NF   8      // number of functions
#define RM   51     // removed leading iterations
#define NCH  64     // chunks per batch
#define CH   128    // NP / NCH, steps per chunk
#define SEG  32     // steps per register-staged segment
#define NSEG 4      // CH / SEG

// compile-time element extract from int4[8] register array (s must be a
// constant after unrolling -> stays in registers, no scratch)
#define ELEM(v, s) ( (((s) & 3) == 0) ? (v)[(s) >> 2].x \
                   : (((s) & 3) == 1) ? (v)[(s) >> 2].y \
                   : (((s) & 3) == 2) ? (v)[(s) >> 2].z \
                   :                    (v)[(s) >> 2].w )

// ws layout: maps (2x float4 per (c,b)) = 4 MB, then pe (float2 per (c,b)) = 1 MB

// ---------------- Phase 1: per-chunk affine composition (pair table) ----------------
__global__ __launch_bounds__(256) void ifs_phase1(
    const int* __restrict__ idxg, const float* __restrict__ W,
    const float* __restrict__ B, float4* __restrict__ maps)
{
    __shared__ __align__(16) float4 pA[64];  // pair matrix {a00,a01,a10,a11}
    __shared__ __align__(16) float2 pC[64];  // pair translation {c0,c1}
    const int tid = threadIdx.x;
    if (tid < 64) {
        const int fb = tid & 7;   // earlier step's function
        const int fa = tid >> 3;  // later step's function
        const float wa00 = W[fa*4+0], wa01 = W[fa*4+1], wa10 = W[fa*4+2], wa11 = W[fa*4+3];
        const float wb00 = W[fb*4+0], wb01 = W[fb*4+1], wb10 = W[fb*4+2], wb11 = W[fb*4+3];
        const float ba0 = B[fa*2+0], ba1 = B[fa*2+1];
        const float bb0 = B[fb*2+0], bb1 = B[fb*2+1];
        pA[tid] = make_float4(wa00*wb00 + wa01*wb10, wa00*wb01 + wa01*wb11,
                              wa10*wb00 + wa11*wb10, wa10*wb01 + wa11*wb11);
        pC[tid] = make_float2(wa00*bb0 + wa01*bb1 + ba0,
                              wa10*bb0 + wa11*bb1 + ba1);
    }
    __syncthreads();

    const int c = blockIdx.x >> 3;
    const int b = ((blockIdx.x & 7) << 8) + tid;
    const int4* ip = (const int4*)(idxg + (size_t)b * NP + c * CH);

    int4 va[8], vb[8];
    #pragma unroll
    for (int k = 0; k < 8; ++k) va[k] = ip[k];

    float a00 = 1.f, a01 = 0.f, a10 = 0.f, a11 = 1.f, c0 = 0.f, c1 = 0.f;

    for (int seg = 0; seg < NSEG; ++seg) {
        if (seg + 1 < NSEG) {
            #pragma unroll
            for (int k = 0; k < 8; ++k) vb[k] = ip[(seg + 1) * 8 + k];
        }
        #pragma unroll
        for (int s = 0; s < SEG; s += 2) {
            const int e = ELEM(va, s + 1) * 8 + ELEM(va, s);
            const float4 P = pA[e];
            const float2 q = pC[e];
            const float na00 = P.x*a00 + P.y*a10;
            const float na01 = P.x*a01 + P.y*a11;
            const float na10 = P.z*a00 + P.w*a10;
            const float na11 = P.z*a01 + P.w*a11;
            const float nc0  = P.x*c0  + P.y*c1 + q.x;
            const float nc1  = P.z*c0  + P.w*c1 + q.y;
            a00 = na00; a01 = na01; a10 = na10; a11 = na11; c0 = nc0; c1 = nc1;
        }
        #pragma unroll
        for (int k = 0; k < 8; ++k) va[k] = vb[k];
    }
    const size_t n = ((size_t)c * MB + b) * 2;
    maps[n]     = make_float4(a00, a01, a10, a11);
    maps[n + 1] = make_float4(c0,  c1,  0.f, 0.f);
}

// ---------------- Phase 2: sequential scan over chunk maps (8-deep prefetch) ----------------
__global__ __launch_bounds__(256) void ifs_phase2(
    const float2* __restrict__ point, const float4* __restrict__ maps,
    float2* __restrict__ pe)
{
    const int b = blockIdx.x * 256 + threadIdx.x;
    float2 p = point[b];
    float4 lo[8], hi[8], nlo[8], nhi[8];
    #pragma unroll
    for (int k = 0; k < 8; ++k) {
        lo[k] = maps[((size_t)k * MB + b) * 2];
        hi[k] = maps[((size_t)k * MB + b) * 2 + 1];
    }
    for (int g = 0; g < 8; ++g) {
        if (g < 7) {
            #pragma unroll
            for (int k = 0; k < 8; ++k) {
                nlo[k] = maps[((size_t)((g + 1) * 8 + k) * MB + b) * 2];
                nhi[k] = maps[((size_t)((g + 1) * 8 + k) * MB + b) * 2 + 1];
            }
        }
        #pragma unroll
        for (int k = 0; k < 8; ++k) {
            pe[(size_t)(g * 8 + k) * MB + b] = p;
            const float nx = lo[k].x * p.x + lo[k].y * p.y + hi[k].x;
            const float ny = lo[k].z * p.x + lo[k].w * p.y + hi[k].y;
            p.x = nx; p.y = ny;
        }
        #pragma unroll
        for (int k = 0; k < 8; ++k) { lo[k] = nlo[k]; hi[k] = nhi[k]; }
    }
}

// ---------------- Phase 3: replay chunks, write outputs ----------------
template <bool CHECK>
__device__ __forceinline__ void phase3_body(
    const int4* ip, const float4* tA, const float4* tB,
    float2 p, float* o, int c)
{
    int4 va[8], vb[8];
    #pragma unroll
    for (int k = 0; k < 8; ++k) va[k] = ip[k];

    for (int seg = 0; seg < NSEG; ++seg) {
        if (seg + 1 < NSEG) {
            #pragma unroll
            for (int k = 0; k < 8; ++k) vb[k] = ip[(seg + 1) * 8 + k];
        }
        #pragma unroll
        for (int s = 0; s < SEG; ++s) {
            const int f = ELEM(va, s);
            const float4 w  = tA[f];
            const float4 bb = tB[f];
            const float nx = w.x * p.x + w.y * p.y + bb.x;
            const float ny = w.z * p.x + w.w * p.y + bb.y;
            p.x = nx; p.y = ny;
            if (!CHECK || (seg * SEG + s) >= RM) {   // c==0 only ever uses CHECK=true
                o[0] = p.x; o[1] = p.y; o[2] = bb.z;
            }
            o += MB * 3;
        }
        #pragma unroll
        for (int k = 0; k < 8; ++k) va[k] = vb[k];
    }
}

__global__ __launch_bounds__(256) void ifs_phase3(
    const int* __restrict__ idxg, const float* __restrict__ W,
    const float* __restrict__ B, const float* __restrict__ OPS,
    const float2* __restrict__ pe, float* __restrict__ out)
{
    __shared__ __align__(16) float4 tA[NF];  // {w00,w01,w10,w11} -> 128B, conflict-free
    __shared__ __align__(16) float4 tB[NF];  // {b0,b1,op,0}      -> 128B, conflict-free
    const int tid = threadIdx.x;
    if (tid < NF) {
        tA[tid] = make_float4(W[tid*4+0], W[tid*4+1], W[tid*4+2], W[tid*4+3]);
        tB[tid] = make_float4(B[tid*2+0], B[tid*2+1], OPS[tid], 0.f);
    }
    __syncthreads();

    const int c = blockIdx.x >> 3;
    const int b = ((blockIdx.x & 7) << 8) + tid;
    const int4* ip = (const int4*)(idxg + (size_t)b * NP + c * CH);

    const float2 p = pe[(size_t)c * MB + b];
    float* o = out + ((long long)c * CH - RM) * (MB * 3) + (long long)b * 3;

    if (c == 0) phase3_body<true >(ip, tA, tB, p, o, c);
    else        phase3_body<false>(ip, tA, tB, p, o, c);
}

extern "C" void kernel_launch(void* const* d_in, const int* in_sizes, int n_in,
                              void* d_out, int out_size, void* d_ws, size_t ws_size,
                              hipStream_t stream) {
    const float* point = (const float*)d_in[0];  // [2048,2,1]
    const float* W     = (const float*)d_in[1];  // [8,2,2]
    const float* B     = (const float*)d_in[2];  // [8,2,1]
    const float* OPS   = (const float*)d_in[3];  // [8]
    const int*   idx   = (const int*)  d_in[4];  // [2048,8192]
    float*       out   = (float*)d_out;          // [(8192-51)*2048, 3]

    float*  ws   = (float*)d_ws;
    float4* maps = (float4*)ws;                               // 4 MB
    float2* pe   = (float2*)(ws + (size_t)NCH * MB * 8);      // 1 MB

    ifs_phase1<<<NCH * (MB / 256), 256, 0, stream>>>(idx, W, B, maps);
    ifs_phase2<<<MB / 256, 256, 0, stream>>>((const float2*)point, maps, pe);
    ifs_phase3<<<NCH * (MB / 256), 256, 0, stream>>>(idx, W, B, OPS, pe, out);
}